// Round 15
// baseline (580.897 us; speedup 1.0000x reference)
//
#include <hip/hip_runtime.h>
#include <math.h>

#define B_    16384
#define N_    1152
#define KPAD  2464   // 1152 + 576 + 576 + 144 (cv23 3-slot) + 16 pad = 77 x 32
#define KLOOP 192    // per-j2: 72 real slots + 24 pad -> 96 = 3 x 32, x2
#define NOUT  4608
#define NT    24     // NOUT/192
#define LOG2F_ 0.69314718055994530942f

typedef unsigned short ushort_t;
typedef __attribute__((ext_vector_type(8))) short short8;
typedef __attribute__((ext_vector_type(4))) float floatx4;

__device__ __forceinline__ float log_cosh_f(float t) {
    float a = fabsf(t);
    return a + __logf(1.0f + __expf(-2.0f * a)) - LOG2F_;
}
__device__ __forceinline__ ushort_t bf16_rne(float f) {
    unsigned int u = __float_as_uint(f);
    return (ushort_t)((u + 0x7fffu + ((u >> 16) & 1u)) >> 16);
}
__device__ __forceinline__ float bf16_to_f(ushort_t h) {
    return __uint_as_float(((unsigned int)h) << 16);
}

typedef __attribute__((address_space(1))) const unsigned int guint;
typedef __attribute__((address_space(3))) unsigned int luint;
__device__ __forceinline__ void gload16(const ushort_t* src, ushort_t* dst) {
    __builtin_amdgcn_global_load_lds((guint*)src, (luint*)dst, 16, 0, 0);
}

// ---------------------------------------------------------------------------
// Kernel 1: gather + transpose + bf16-encode weights. (unchanged)
// ---------------------------------------------------------------------------
__global__ __launch_bounds__(256) void build_w(
    const int* __restrict__ symm,
    const int* __restrict__ c0s, const int* __restrict__ c1s,
    const int* __restrict__ c2s, const int* __restrict__ c3s,
    const float* __restrict__ sk,
    const float* __restrict__ ck0, const float* __restrict__ ck1,
    const float* __restrict__ ck2, const float* __restrict__ ck3,
    const float* __restrict__ l0k, const float* __restrict__ l1k,
    ushort_t* __restrict__ Wb, ushort_t* __restrict__ LWb)
{
    __shared__ int idx[2352];
    const int s = blockIdx.x;
    const int tid = threadIdx.x;
    for (int i = tid; i < 1152; i += 256) idx[i] = symm[s * N_ + i];
    for (int i = tid; i < 576; i += 256) idx[1152 + i] = c0s[s * 576 + i];
    for (int i = tid; i < 576; i += 256) idx[1728 + i] = c1s[s * 576 + i];
    if (tid < 24) idx[2304 + tid] = c2s[s * 24 + tid];
    else if (tid < 48) idx[2328 + (tid - 24)] = c3s[s * 24 + (tid - 24)];
    __syncthreads();
    for (int f = 0; f < 8; ++f) {
        ushort_t* wr = Wb + (size_t)(s * 8 + f) * KPAD;
        for (int k = tid; k < KPAD; k += 256) {
            ushort_t o;
            if (k < 1152)      o = bf16_rne(sk[f * N_ + idx[k]]);
            else if (k < 1728) o = bf16_rne(ck0[f * 576 + idx[k]]);
            else if (k < 2304) o = bf16_rne(ck1[f * 576 + idx[k]]);
            else if (k < 2448) {
                int q = k - 2304, g = q / 48, c = q - g * 48;
                float w = (c < 24) ? ck2[f * 24 + idx[2304 + c]]
                                   : ck3[f * 24 + idx[2328 + (c - 24)]];
                ushort_t hi = bf16_rne(w);
                o = (g < 2) ? hi : bf16_rne(w - bf16_to_f(hi));
            } else o = 0;
            wr[k] = o;
        }
        ushort_t* lr = LWb + (size_t)(s * 8 + f) * KLOOP;
        for (int k2 = tid; k2 < KLOOP; k2 += 256) {
            int j2 = k2 / 96, q = k2 - j2 * 96;
            ushort_t o = 0;
            if (q < 72) {
                int g = q / 24, c = q - g * 24;
                float w = j2 ? l1k[f * 24 + idx[2328 + c]]
                             : l0k[f * 24 + idx[2304 + c]];
                ushort_t hi = bf16_rne(w);
                o = (g < 2) ? hi : bf16_rne(w - bf16_to_f(hi));
            }
            lr[k2] = o;
        }
    }
}

// ---------------------------------------------------------------------------
// Kernel 2: augmented A matrix (bf16) + loop-cv matrix + scalar bias. (same)
// ---------------------------------------------------------------------------
__global__ __launch_bounds__(256) void build_cv(
    const float* __restrict__ x,
    const int* __restrict__ corr0, const int* __restrict__ corr1,
    const int* __restrict__ corr2, const int* __restrict__ corr3,
    const float* __restrict__ vb,
    const float* __restrict__ cb0, const float* __restrict__ cb1,
    const float* __restrict__ cb2, const float* __restrict__ cb3,
    ushort_t* __restrict__ XA, ushort_t* __restrict__ CVL,
    float* __restrict__ initb)
{
    __shared__ float xs[N_];
    __shared__ float red[256];
    __shared__ float cvhi[48], cvlo[48];
    const int tid = threadIdx.x;
    const int b = blockIdx.x;
    ushort_t* xr = XA + (size_t)b * KPAD;

    float bias = 0.f;
    const float vb0 = vb[0], vb1 = vb[1];
    for (int i = tid; i < N_; i += 256) {
        float v = x[(size_t)b * N_ + i];
        xs[i] = v;
        bias += v * ((i & 1) ? vb1 : vb0);
        xr[i] = bf16_rne(v);
    }
    __syncthreads();
    float s0 = 0.f, s1 = 0.f, s2 = 0.f, s3 = 0.f;
    for (int c = tid; c < 576; c += 256) {
        const int* i0 = corr0 + c * 4;
        float p = xs[i0[0]] * xs[i0[1]] * xs[i0[2]] * xs[i0[3]];
        xr[1152 + c] = bf16_rne(p); s0 += p;
        const int* i1 = corr1 + c * 4;
        float q = xs[i1[0]] * xs[i1[1]] * xs[i1[2]] * xs[i1[3]];
        xr[1728 + c] = bf16_rne(q); s1 += q;
    }
    if (tid < 48) {
        int j2 = tid / 24, c = tid - j2 * 24;
        const int* ii = (j2 ? corr3 : corr2) + c * 24;
        float p = 1.f;
        for (int j = 0; j < 24; ++j) p *= xs[ii[j]];
        float hv = bf16_to_f(bf16_rne(p));
        cvhi[tid] = hv;
        cvlo[tid] = p - hv;
        if (j2) s3 = p; else s2 = p;
    }
    __syncthreads();
    for (int i = tid; i < KPAD - 2304; i += 256) {
        ushort_t o = 0;
        if (i < 144) {
            int g = i / 48, c = i - g * 48;
            o = bf16_rne(g == 1 ? cvlo[c] : cvhi[c]);
        }
        xr[2304 + i] = o;
    }
    ushort_t* cr = CVL + (size_t)b * KLOOP;
    for (int k2 = tid; k2 < KLOOP; k2 += 256) {
        int j2 = k2 / 96, q = k2 - j2 * 96;
        ushort_t o = 0;
        if (q < 72) {
            int g = q / 24, c = q - g * 24;
            o = bf16_rne(g == 1 ? cvlo[j2 * 24 + c] : cvhi[j2 * 24 + c]);
        }
        cr[k2] = o;
    }
    bias += cb0[0] * s0 + cb1[0] * s1 + cb2[0] * s2 + cb3[0] * s3;
    red[tid] = bias;
    __syncthreads();
    for (int off = 128; off; off >>= 1) {
        if (tid < off) red[tid] += red[tid + off];
        __syncthreads();
    }
    if (tid == 0) initb[b] = red[0];
}

// ---------------------------------------------------------------------------
// Kernel 3: 128x192-tile MFMA GEMM, 4 waves (2M x 2N), WAVE TILE 64x96
// (acc 96 regs -> total ~165 <= 170 => 3 waves/SIMD, forced by
// __launch_bounds__(256,3)). BK=32, TWO 20KB buffers (41.5KB) -> 3 blocks/CU
// = 12 waves/CU (1.5x R13's TLP; R13 was jointly LDS+reg capped at 2/SIMD).
// Drain schedule (2 buffers): per tile: vmcnt(0); s_barrier; STAGE(next buf);
// sched_barrier; 10 ds_reads; 24 MFMA. Write safety: stage(t+1) hits the
// buffer whose reads completed before tile t-1's MFMAs issued (operand dep),
// hence before this barrier; barrier syncs all waves.
// Swizzle: stage-src oct=(tid&3)^((srow>>1)&3), read oct=lg^((lrow>>1)&3)
// (R5/7/9/10/12/13-verified pair, 0 conflicts). No setprio (m190).
// ---------------------------------------------------------------------------
__global__ __launch_bounds__(256, 3) void mfma_gemm(
    const ushort_t* __restrict__ XA, const ushort_t* __restrict__ Wb,
    const ushort_t* __restrict__ CVL, const ushort_t* __restrict__ LWb,
    const float* __restrict__ hidden_bias,
    const float* __restrict__ l0hb, const float* __restrict__ l1hb,
    float* __restrict__ partials)
{
    __shared__ __align__(16) ushort_t sh[20480];  // 2 bufs x (A 4096 | B 6144)
    __shared__ float redsh[384];                  // [128 rows][3]

    const int tid = threadIdx.x;
    const int l = tid & 63, w = tid >> 6;
    const int wm = w >> 1, wn = w & 1;            // 2M x 2N waves
    const int lrow = l & 15, lg = l >> 4;
    const int srow = tid >> 2;                    // 0..63
    const int sgr = ((tid & 3) ^ ((srow >> 1) & 3)) * 8;  // stage src swizzle
    const int wb512 = w * 512;                    // wave stage-dest base (us)

    // bijective XCD swizzle: 3072 blocks = 8 chunks x 384, bt-fastest
    // (128 consecutive blocks share one 0.95MB B panel -> L2-hot)
    const int bid = blockIdx.x;
    const int swz = (bid & 7) * 384 + (bid >> 3);
    const int nt = swz >> 7, bt = swz & 127;      // 24 nt x 128 bt
    const int n0 = nt * 192, b0 = bt * 128;

    // persistent per-lane global sources (A: 2 row-chunks, B: 3)
    const ushort_t* pa0 = XA + (size_t)(b0 + srow) * KPAD + sgr;
    const ushort_t* pa1 = pa0 + (size_t)64 * KPAD;
    const ushort_t* pb0 = Wb + (size_t)(n0 + srow) * KPAD + sgr;
    const ushort_t* pb1 = pb0 + (size_t)64 * KPAD;
    const ushort_t* pb2 = pb0 + (size_t)128 * KPAD;

    // frag read bases: A [128][32] at 0; B [192][32] at 4096 (us)
    const int oct = (lg ^ ((lrow >> 1) & 3)) * 8;
    const int aoff = (wm * 64 + lrow) * 32 + oct;
    const int boff = 4096 + (wn * 96 + lrow) * 32 + oct;

    floatx4 acc[4][6];

    auto STAGE = [&](int buf, int off) {   // one 128x32 A + 192x32 B tile
        gload16(pa0 + off, &sh[buf + 0    + wb512]);
        gload16(pa1 + off, &sh[buf + 2048 + wb512]);
        gload16(pb0 + off, &sh[buf + 4096 + wb512]);
        gload16(pb1 + off, &sh[buf + 6144 + wb512]);
        gload16(pb2 + off, &sh[buf + 8192 + wb512]);
    };
    auto TILE = [&](int buf) {             // 10 ds_read_b128 + 24 MFMA
        short8 af[4], bf[6];
#pragma unroll
        for (int mi = 0; mi < 4; ++mi)
            af[mi] = *(const short8*)&sh[buf + aoff + mi * 512];
#pragma unroll
        for (int ni = 0; ni < 6; ++ni)
            bf[ni] = *(const short8*)&sh[buf + boff + ni * 512];
#pragma unroll
        for (int mi = 0; mi < 4; ++mi)
#pragma unroll
            for (int ni = 0; ni < 6; ++ni)
                acc[mi][ni] = __builtin_amdgcn_mfma_f32_16x16x32_bf16(
                    af[mi], bf[ni], acc[mi][ni], 0, 0, 0);
    };
#define VMB0() do { asm volatile("s_waitcnt vmcnt(0)" ::: "memory"); \
    __builtin_amdgcn_s_barrier(); } while (0)
#define SB0() __builtin_amdgcn_sched_barrier(0)

#pragma unroll
    for (int mi = 0; mi < 4; ++mi)
#pragma unroll
        for (int ni = 0; ni < 6; ++ni) acc[mi][ni] = (floatx4){0.f, 0.f, 0.f, 0.f};

    // ---- main loop: 77 tiles, 2 buffers, stage-next-during-compute ----
    STAGE(0, 0);                              // tile 0 -> buf0
#pragma unroll 1
    for (int m = 0; m < 38; ++m) {            // tiles 0..75; stages 1..76
        VMB0(); STAGE(10240, 32); SB0(); TILE(0);      // t=2m,   stage 2m+1
        VMB0(); STAGE(0, 64);     SB0(); TILE(10240);  // t=2m+1, stage 2m+2
        pa0 += 64; pa1 += 64; pb0 += 64; pb1 += 64; pb2 += 64;
    }
    VMB0(); TILE(0);                                   // t=76 (buf0)

    // ---- main log_cosh rowsums -> redsh (D: row=lg*4+reg, col=lrow) ----
    {
        const float hbv = hidden_bias[l & 7];
#pragma unroll
        for (int mi = 0; mi < 4; ++mi)
#pragma unroll
            for (int reg = 0; reg < 4; ++reg) {
                float v = 0.f;
#pragma unroll
                for (int ni = 0; ni < 6; ++ni)
                    v += log_cosh_f(acc[mi][ni][reg] + hbv);
                v += __shfl_xor(v, 1); v += __shfl_xor(v, 2);
                v += __shfl_xor(v, 4); v += __shfl_xor(v, 8);
                if (lrow == 0)
                    redsh[(wm * 64 + mi * 16 + lg * 4 + reg) * 3 + wn] = v;
            }
    }

    // ---- loop-correlator mini-GEMMs (K=96 per j2 = 3 tiles), drain style ---
    const ushort_t* pc0 = CVL + (size_t)(b0 + srow) * KLOOP + sgr;
    const ushort_t* pc1 = pc0 + (size_t)64 * KLOOP;
    const ushort_t* pl0 = LWb + (size_t)(n0 + srow) * KLOOP + sgr;
    const ushort_t* pl1 = pl0 + (size_t)64 * KLOOP;
    const ushort_t* pl2 = pl0 + (size_t)128 * KLOOP;
    auto STGm = [&](int buf, int off) {
        gload16(pc0 + off, &sh[buf + 0    + wb512]);
        gload16(pc1 + off, &sh[buf + 2048 + wb512]);
        gload16(pl0 + off, &sh[buf + 4096 + wb512]);
        gload16(pl1 + off, &sh[buf + 6144 + wb512]);
        gload16(pl2 + off, &sh[buf + 8192 + wb512]);
    };
#pragma unroll
    for (int j2 = 0; j2 < 2; ++j2) {
#pragma unroll
        for (int mi = 0; mi < 4; ++mi)
#pragma unroll
            for (int ni = 0; ni < 6; ++ni) acc[mi][ni] = (floatx4){0.f, 0.f, 0.f, 0.f};
        __syncthreads();                          // drains all reads+loads
        const int kb = j2 * 96;
        STGm(0, kb); STGm(10240, kb + 32);
        __syncthreads();                          // k0,k1 resident
        TILE(0); TILE(10240);
        __syncthreads();                          // buf0 reads complete
        STGm(0, kb + 64);
        __syncthreads();                          // k2 resident
        TILE(0);
        const float lbv = (j2 ? l1hb : l0hb)[l & 7];
#pragma unroll
        for (int mi = 0; mi < 4; ++mi)
#pragma unroll
            for (int reg = 0; reg < 4; ++reg) {
                float v = 0.f;
#pragma unroll
                for (int ni = 0; ni < 6; ++ni)
                    v += log_cosh_f(acc[mi][ni][reg] + lbv);
                v += __shfl_xor(v, 1); v += __shfl_xor(v, 2);
                v += __shfl_xor(v, 4); v += __shfl_xor(v, 8);
                if (lrow == 0)
                    redsh[(wm * 64 + mi * 16 + lg * 4 + reg) * 3 + wn] += v;
            }
    }

    // ---- final cross-wave sum (128 rows, wn in {0,1}) ----
    __syncthreads();
    if (tid < 128) {
        float t = redsh[tid * 3 + 0] + redsh[tid * 3 + 1];
        partials[(size_t)nt * B_ + b0 + tid] = t;
    }
#undef VMB0
#undef SB0
}

// ---------------------------------------------------------------------------
// Kernel 4: out[b] = initb[b] + sum over n-tiles
// ---------------------------------------------------------------------------
__global__ __launch_bounds__(256) void finalize_out(
    const float* __restrict__ initb, const float* __restrict__ partials,
    float* __restrict__ out)
{
    int b = blockIdx.x * 256 + threadIdx.x;
    float s = initb[b];
#pragma unroll
    for (int t = 0; t < NT; ++t) s += partials[(size_t)t * B_ + b];
    out[b] = s;
}

extern "C" void kernel_launch(void* const* d_in, const int* in_sizes, int n_in,
                              void* d_out, int out_size, void* d_ws, size_t ws_size,
                              hipStream_t stream) {
    const float* x    = (const float*)d_in[0];
    const int* symm   = (const int*)d_in[1];
    const int* corr0  = (const int*)d_in[2];
    const int* corr1  = (const int*)d_in[3];
    const int* corr2  = (const int*)d_in[4];
    const int* corr3  = (const int*)d_in[5];
    const int* c0s    = (const int*)d_in[6];
    const int* c1s    = (const int*)d_in[7];
    const int* c2s    = (const int*)d_in[8];
    const int* c3s    = (const int*)d_in[9];
    const float* hb   = (const float*)d_in[10];
    const float* sk   = (const float*)d_in[11];
    const float* vb   = (const float*)d_in[12];
    const float* cb0  = (const float*)d_in[13];
    const float* ck0  = (const float*)d_in[14];
    const float* cb1  = (const float*)d_in[15];
    const float* ck1  = (const float*)d_in[16];
    const float* cb2  = (const float*)d_in[17];
    const float* ck2  = (const float*)d_in[18];
    const float* cb3  = (const float*)d_in[19];
    const float* ck3  = (const float*)d_in[20];
    const float* l0hb = (const float*)d_in[21];
    const float* l0k  = (const float*)d_in[22];
    const float* l1hb = (const float*)d_in[23];
    const float* l1k  = (const float*)d_in[24];

    ushort_t* wsu = (ushort_t*)d_ws;
    ushort_t* Wb  = wsu;                            // 4608*2464
    ushort_t* XA  = Wb + (size_t)NOUT * KPAD;       // 16384*2464
    ushort_t* LWb = XA + (size_t)B_ * KPAD;         // 4608*192
    ushort_t* CVL = LWb + (size_t)NOUT * KLOOP;     // 16384*192
    float* initb    = (float*)(CVL + (size_t)B_ * KLOOP);  // 16384
    float* partials = initb + B_;                          // 24*16384

    build_w<<<576, 256, 0, stream>>>(
        symm, c0s, c1s, c2s, c3s, sk, ck0, ck1, ck2, ck3, l0k, l1k, Wb, LWb);
    build_cv<<<B_, 256, 0, stream>>>(
        x, corr0, corr1, corr2, corr3, vb, cb0, cb1, cb2, cb3, XA, CVL, initb);
    mfma_gemm<<<3072, 256, 0, stream>>>(
        XA, Wb, CVL, LWb, hb, l0hb, l1hb, partials);
    finalize_out<<<B_ / 256, 256, 0, stream>>>(initb, partials, (float*)d_out);
}

// Round 16
// 544.719 us; speedup vs baseline: 1.0664x; 1.0664x over previous
//
#include <hip/hip_runtime.h>
#include <math.h>

#define B_    16384
#define N_    1152
#define KPAD  2464   // 1152 + 576 + 576 + 144 (cv23 3-slot) + 16 pad = 77 x 32
#define KLOOP 192    // per-j2: 72 real slots + 24 pad -> 96 = 3 x 32, x2
#define NOUT  4608
#define NT    18     // NOUT/256
#define LOG2F_ 0.69314718055994530942f

typedef unsigned short ushort_t;
typedef __attribute__((ext_vector_type(8))) short short8;
typedef __attribute__((ext_vector_type(4))) float floatx4;

__device__ __forceinline__ float log_cosh_f(float t) {
    float a = fabsf(t);
    return a + __logf(1.0f + __expf(-2.0f * a)) - LOG2F_;
}
__device__ __forceinline__ ushort_t bf16_rne(float f) {
    unsigned int u = __float_as_uint(f);
    return (ushort_t)((u + 0x7fffu + ((u >> 16) & 1u)) >> 16);
}
__device__ __forceinline__ float bf16_to_f(ushort_t h) {
    return __uint_as_float(((unsigned int)h) << 16);
}

typedef __attribute__((address_space(1))) const unsigned int guint;
typedef __attribute__((address_space(3))) unsigned int luint;
__device__ __forceinline__ void gload16(const ushort_t* src, ushort_t* dst) {
    __builtin_amdgcn_global_load_lds((guint*)src, (luint*)dst, 16, 0, 0);
}

// ---------------------------------------------------------------------------
// Kernel 1: gather + transpose + bf16-encode weights.
//   Wb[n][k] bf16, n=s*8+f; k<2304 plain; [2304,2448) 3-slot hi/lo for cv2/3
//   (g=0: w_hi, g=1: w_hi, g=2: w_lo); [2448,KPAD) zero.
//   LWb[n][k2] bf16, k2 = j2*96 + g*24 + c (g as above), pad zero.
// ---------------------------------------------------------------------------
__global__ __launch_bounds__(256) void build_w(
    const int* __restrict__ symm,
    const int* __restrict__ c0s, const int* __restrict__ c1s,
    const int* __restrict__ c2s, const int* __restrict__ c3s,
    const float* __restrict__ sk,
    const float* __restrict__ ck0, const float* __restrict__ ck1,
    const float* __restrict__ ck2, const float* __restrict__ ck3,
    const float* __restrict__ l0k, const float* __restrict__ l1k,
    ushort_t* __restrict__ Wb, ushort_t* __restrict__ LWb)
{
    __shared__ int idx[2352];
    const int s = blockIdx.x;
    const int tid = threadIdx.x;
    for (int i = tid; i < 1152; i += 256) idx[i] = symm[s * N_ + i];
    for (int i = tid; i < 576; i += 256) idx[1152 + i] = c0s[s * 576 + i];
    for (int i = tid; i < 576; i += 256) idx[1728 + i] = c1s[s * 576 + i];
    if (tid < 24) idx[2304 + tid] = c2s[s * 24 + tid];
    else if (tid < 48) idx[2328 + (tid - 24)] = c3s[s * 24 + (tid - 24)];
    __syncthreads();
    for (int f = 0; f < 8; ++f) {
        ushort_t* wr = Wb + (size_t)(s * 8 + f) * KPAD;
        for (int k = tid; k < KPAD; k += 256) {
            ushort_t o;
            if (k < 1152)      o = bf16_rne(sk[f * N_ + idx[k]]);
            else if (k < 1728) o = bf16_rne(ck0[f * 576 + idx[k]]);
            else if (k < 2304) o = bf16_rne(ck1[f * 576 + idx[k]]);
            else if (k < 2448) {
                int q = k - 2304, g = q / 48, c = q - g * 48;
                float w = (c < 24) ? ck2[f * 24 + idx[2304 + c]]
                                   : ck3[f * 24 + idx[2328 + (c - 24)]];
                ushort_t hi = bf16_rne(w);
                o = (g < 2) ? hi : bf16_rne(w - bf16_to_f(hi));
            } else o = 0;
            wr[k] = o;
        }
        ushort_t* lr = LWb + (size_t)(s * 8 + f) * KLOOP;
        for (int k2 = tid; k2 < KLOOP; k2 += 256) {
            int j2 = k2 / 96, q = k2 - j2 * 96;
            ushort_t o = 0;
            if (q < 72) {
                int g = q / 24, c = q - g * 24;
                float w = j2 ? l1k[f * 24 + idx[2328 + c]]
                             : l0k[f * 24 + idx[2304 + c]];
                ushort_t hi = bf16_rne(w);
                o = (g < 2) ? hi : bf16_rne(w - bf16_to_f(hi));
            }
            lr[k2] = o;
        }
    }
}

// ---------------------------------------------------------------------------
// Kernel 2: augmented A matrix (bf16) + loop-cv matrix + scalar bias.
//   XA[b][k]: x | cv0 | cv1 | cv23 3-slot (g=0: cv_hi, g=1: cv_lo,
//   g=2: cv_hi) | 0.  CVL[b][k2]: per j2 (stride 96): hi,lo,hi x24 | 0-pad.
// ---------------------------------------------------------------------------
__global__ __launch_bounds__(256) void build_cv(
    const float* __restrict__ x,
    const int* __restrict__ corr0, const int* __restrict__ corr1,
    const int* __restrict__ corr2, const int* __restrict__ corr3,
    const float* __restrict__ vb,
    const float* __restrict__ cb0, const float* __restrict__ cb1,
    const float* __restrict__ cb2, const float* __restrict__ cb3,
    ushort_t* __restrict__ XA, ushort_t* __restrict__ CVL,
    float* __restrict__ initb)
{
    __shared__ float xs[N_];
    __shared__ float red[256];
    __shared__ float cvhi[48], cvlo[48];
    const int tid = threadIdx.x;
    const int b = blockIdx.x;
    ushort_t* xr = XA + (size_t)b * KPAD;

    float bias = 0.f;
    const float vb0 = vb[0], vb1 = vb[1];
    for (int i = tid; i < N_; i += 256) {
        float v = x[(size_t)b * N_ + i];
        xs[i] = v;
        bias += v * ((i & 1) ? vb1 : vb0);
        xr[i] = bf16_rne(v);
    }
    __syncthreads();
    float s0 = 0.f, s1 = 0.f, s2 = 0.f, s3 = 0.f;
    for (int c = tid; c < 576; c += 256) {
        const int* i0 = corr0 + c * 4;
        float p = xs[i0[0]] * xs[i0[1]] * xs[i0[2]] * xs[i0[3]];
        xr[1152 + c] = bf16_rne(p); s0 += p;
        const int* i1 = corr1 + c * 4;
        float q = xs[i1[0]] * xs[i1[1]] * xs[i1[2]] * xs[i1[3]];
        xr[1728 + c] = bf16_rne(q); s1 += q;
    }
    if (tid < 48) {
        int j2 = tid / 24, c = tid - j2 * 24;
        const int* ii = (j2 ? corr3 : corr2) + c * 24;
        float p = 1.f;
        for (int j = 0; j < 24; ++j) p *= xs[ii[j]];
        float hv = bf16_to_f(bf16_rne(p));
        cvhi[tid] = hv;
        cvlo[tid] = p - hv;
        if (j2) s3 = p; else s2 = p;
    }
    __syncthreads();
    for (int i = tid; i < KPAD - 2304; i += 256) {
        ushort_t o = 0;
        if (i < 144) {
            int g = i / 48, c = i - g * 48;
            o = bf16_rne(g == 1 ? cvlo[c] : cvhi[c]);
        }
        xr[2304 + i] = o;
    }
    ushort_t* cr = CVL + (size_t)b * KLOOP;
    for (int k2 = tid; k2 < KLOOP; k2 += 256) {
        int j2 = k2 / 96, q = k2 - j2 * 96;
        ushort_t o = 0;
        if (q < 72) {
            int g = q / 24, c = q - g * 24;
            o = bf16_rne(g == 1 ? cvlo[j2 * 24 + c] : cvhi[j2 * 24 + c]);
        }
        cr[k2] = o;
    }
    bias += cb0[0] * s0 + cb1[0] * s1 + cb2[0] * s2 + cb3[0] * s3;
    red[tid] = bias;
    __syncthreads();
    for (int off = 128; off; off >>= 1) {
        if (tid < off) red[tid] += red[tid + off];
        __syncthreads();
    }
    if (tid == 0) initb[b] = red[0];
}

// ---------------------------------------------------------------------------
// Kernel 3: 128x256-tile MFMA GEMM (best measured structure: ~529us GEMM,
// 545us total). KPAD=2464 (77 K-tiles). 4 waves (2M x 2N), WAVE TILE 64x128
// (12 ds_reads / 32 MFMA = 0.375), BK=32, THREE 24KB buffers -> 2 blocks/CU.
// BN=256 -> 18 n-tile groups: FETCH ~836MB (measured). Schedule:
//   tile t: vmcnt(6); s_barrier; STAGE(t+2); sched_barrier; 12 ds_reads;
//           32 MFMA (compiler partial-lgkmcnt interleaves).
// vmcnt(6): at tile-t barrier only stage(t+1)'s 6 gloads are newer => stage(t)
// complete. Write safety: stage(t+2)'s buffer was last read at tile t-1 and
// those reads completed before t-1's MFMAs issued, hence before this barrier.
// Peel: 77 = 25x3 + 2; after m=24, outstanding = stage(75)@buf0 + stage(76)
// @buf1 -> t=75: vmcnt(6) proves stage(75) done; t=76: vmcnt(0).
// Swizzle: stage-src oct=(tid&3)^((srow>>1)&3), read oct=lg^((lrow>>1)&3)
// (verified 0 conflicts across 6 rounds). No setprio (m190).
// Axes closed by measurement: schedule depth (R4-R8 null), LDS ratio (R9-10),
// fetch geometry (R12), occupancy up (R11 67% worse, R15 33% worse).
// ---------------------------------------------------------------------------
__global__ __launch_bounds__(256, 2) void mfma_gemm(
    const ushort_t* __restrict__ XA, const ushort_t* __restrict__ Wb,
    const ushort_t* __restrict__ CVL, const ushort_t* __restrict__ LWb,
    const float* __restrict__ hidden_bias,
    const float* __restrict__ l0hb, const float* __restrict__ l1hb,
    float* __restrict__ partials)
{
    __shared__ __align__(16) ushort_t sh[36864];  // 3 bufs x (A 4096 | B 8192)
    __shared__ float redsh[384];                  // [128 rows][3]

    const int tid = threadIdx.x;
    const int l = tid & 63, w = tid >> 6;
    const int wm = w >> 1, wn = w & 1;            // 2M x 2N waves
    const int lrow = l & 15, lg = l >> 4;
    const int srow = tid >> 2;                    // 0..63
    const int sgr = ((tid & 3) ^ ((srow >> 1) & 3)) * 8;  // stage src swizzle
    const int wb512 = w * 512;                    // wave stage-dest base (us)

    // bijective XCD swizzle: 2304 blocks = 8 chunks x 288, bt-fastest
    // (128 consecutive blocks share one 1.23MB B panel -> L2-hot)
    const int bid = blockIdx.x;
    const int swz = (bid & 7) * 288 + (bid >> 3);
    const int nt = swz >> 7, bt = swz & 127;      // 18 nt x 128 bt
    const int n0 = nt * 256, b0 = bt * 128;

    // persistent per-lane global sources (A: 2 row-chunks, B: 4)
    const ushort_t* pa0 = XA + (size_t)(b0 + srow) * KPAD + sgr;
    const ushort_t* pa1 = pa0 + (size_t)64 * KPAD;
    const ushort_t* pb0 = Wb + (size_t)(n0 + srow) * KPAD + sgr;
    const ushort_t* pb1 = pb0 + (size_t)64 * KPAD;
    const ushort_t* pb2 = pb0 + (size_t)128 * KPAD;
    const ushort_t* pb3 = pb0 + (size_t)192 * KPAD;

    // frag read bases: A [128][32] at 0; B [256][32] at 4096 (us)
    const int oct = (lg ^ ((lrow >> 1) & 3)) * 8;
    const int aoff = (wm * 64 + lrow) * 32 + oct;
    const int boff = 4096 + (wn * 128 + lrow) * 32 + oct;

    floatx4 acc[4][8];

    auto STAGE = [&](int buf, int off) {   // one 128x32 A + 256x32 B tile
        gload16(pa0 + off, &sh[buf + 0     + wb512]);
        gload16(pa1 + off, &sh[buf + 2048  + wb512]);
        gload16(pb0 + off, &sh[buf + 4096  + wb512]);
        gload16(pb1 + off, &sh[buf + 6144  + wb512]);
        gload16(pb2 + off, &sh[buf + 8192  + wb512]);
        gload16(pb3 + off, &sh[buf + 10240 + wb512]);
    };
    auto TILE = [&](int buf) {
        short8 af[4], bf[8];
#pragma unroll
        for (int mi = 0; mi < 4; ++mi)
            af[mi] = *(const short8*)&sh[buf + aoff + mi * 512];
#pragma unroll
        for (int ni = 0; ni < 8; ++ni)
            bf[ni] = *(const short8*)&sh[buf + boff + ni * 512];
#pragma unroll
        for (int mi = 0; mi < 4; ++mi)
#pragma unroll
            for (int ni = 0; ni < 8; ++ni)
                acc[mi][ni] = __builtin_amdgcn_mfma_f32_16x16x32_bf16(
                    af[mi], bf[ni], acc[mi][ni], 0, 0, 0);
    };
#define VMB(N) do { asm volatile("s_waitcnt vmcnt(" #N ")" ::: "memory"); \
    __builtin_amdgcn_s_barrier(); } while (0)
#define SB0() __builtin_amdgcn_sched_barrier(0)

#pragma unroll
    for (int mi = 0; mi < 4; ++mi)
#pragma unroll
        for (int ni = 0; ni < 8; ++ni) acc[mi][ni] = (floatx4){0.f, 0.f, 0.f, 0.f};

    // ---- prologue: stage tiles 0,1 ----
    STAGE(0, 0); STAGE(12288, 32);

    // ---- main loop: 77 tiles = 25 x 3 + peel(75,76); base bumps 96/iter ----
#pragma unroll 1
    for (int m = 0; m < 25; ++m) {
        VMB(6); STAGE(24576, 64);  SB0(); TILE(0);       // t=3m,   stage 3m+2
        VMB(6); STAGE(0, 96);      SB0(); TILE(12288);   // t=3m+1, stage 3m+3
        VMB(6); STAGE(12288, 128); SB0(); TILE(24576);   // t=3m+2, stage 3m+4
        pa0 += 96; pa1 += 96; pb0 += 96; pb1 += 96; pb2 += 96; pb3 += 96;
    }
    VMB(6); TILE(0);                                     // t=75 (buf0)
    VMB(0); TILE(12288);                                 // t=76 (buf1)

    // ---- main log_cosh rowsums -> redsh (D: row=lg*4+reg, col=lrow) ----
    {
        const float hbv = hidden_bias[l & 7];
#pragma unroll
        for (int mi = 0; mi < 4; ++mi)
#pragma unroll
            for (int reg = 0; reg < 4; ++reg) {
                float v = 0.f;
#pragma unroll
                for (int ni = 0; ni < 8; ++ni)
                    v += log_cosh_f(acc[mi][ni][reg] + hbv);
                v += __shfl_xor(v, 1); v += __shfl_xor(v, 2);
                v += __shfl_xor(v, 4); v += __shfl_xor(v, 8);
                if (lrow == 0)
                    redsh[(wm * 64 + mi * 16 + lg * 4 + reg) * 3 + wn] = v;
            }
    }

    // ---- loop-correlator mini-GEMMs (K=96 per j2 = 3 tiles), drain style ---
    const ushort_t* pc0 = CVL + (size_t)(b0 + srow) * KLOOP + sgr;
    const ushort_t* pc1 = pc0 + (size_t)64 * KLOOP;
    const ushort_t* pl0 = LWb + (size_t)(n0 + srow) * KLOOP + sgr;
    const ushort_t* pl1 = pl0 + (size_t)64 * KLOOP;
    const ushort_t* pl2 = pl0 + (size_t)128 * KLOOP;
    const ushort_t* pl3 = pl0 + (size_t)192 * KLOOP;
    auto STGm = [&](int buf, int off) {
        gload16(pc0 + off, &sh[buf + 0     + wb512]);
        gload16(pc1 + off, &sh[buf + 2048  + wb512]);
        gload16(pl0 + off, &sh[buf + 4096  + wb512]);
        gload16(pl1 + off, &sh[buf + 6144  + wb512]);
        gload16(pl2 + off, &sh[buf + 8192  + wb512]);
        gload16(pl3 + off, &sh[buf + 10240 + wb512]);
    };
#pragma unroll
    for (int j2 = 0; j2 < 2; ++j2) {
#pragma unroll
        for (int mi = 0; mi < 4; ++mi)
#pragma unroll
            for (int ni = 0; ni < 8; ++ni) acc[mi][ni] = (floatx4){0.f, 0.f, 0.f, 0.f};
        __syncthreads();                          // drains all reads+loads
        const int kb = j2 * 96;
        STGm(0, kb); STGm(12288, kb + 32); STGm(24576, kb + 64);
        __syncthreads();                          // all 3 tiles resident
        TILE(0); TILE(12288); TILE(24576);
        const float lbv = (j2 ? l1hb : l0hb)[l & 7];
#pragma unroll
        for (int mi = 0; mi < 4; ++mi)
#pragma unroll
            for (int reg = 0; reg < 4; ++reg) {
                float v = 0.f;
#pragma unroll
                for (int ni = 0; ni < 8; ++ni)
                    v += log_cosh_f(acc[mi][ni][reg] + lbv);
                v += __shfl_xor(v, 1); v += __shfl_xor(v, 2);
                v += __shfl_xor(v, 4); v += __shfl_xor(v, 8);
                if (lrow == 0)
                    redsh[(wm * 64 + mi * 16 + lg * 4 + reg) * 3 + wn] += v;
            }
    }

    // ---- final cross-wave sum (128 rows, wn in {0,1}) ----
    __syncthreads();
    if (tid < 128) {
        float t = redsh[tid * 3 + 0] + redsh[tid * 3 + 1];
        partials[(size_t)nt * B_ + b0 + tid] = t;
    }
#undef VMB
#undef SB0
}

// ---------------------------------------------------------------------------
// Kernel 4: out[b] = initb[b] + sum over n-tiles
// ---------------------------------------------------------------------------
__global__ __launch_bounds__(256) void finalize_out(
    const float* __restrict__ initb, const float* __restrict__ partials,
    float* __restrict__ out)
{
    int b = blockIdx.x * 256 + threadIdx.x;
    float s = initb[b];
#pragma unroll
    for (int t = 0; t < NT; ++t) s += partials[(size_t)t * B_ + b];
    out[b] = s;
}

extern "C" void kernel_launch(void* const* d_in, const int* in_sizes, int n_in,
                              void* d_out, int out_size, void* d_ws, size_t ws_size,
                              hipStream_t stream) {
    const float* x    = (const float*)d_in[0];
    const int* symm   = (const int*)d_in[1];
    const int* corr0  = (const int*)d_in[2];
    const int* corr1  = (const int*)d_in[3];
    const int* corr2  = (const int*)d_in[4];
    const int* corr3  = (const int*)d_in[5];
    const int* c0s    = (const int*)d_in[6];
    const int* c1s    = (const int*)d_in[7];
    const int* c2s    = (const int*)d_in[8];
    const int* c3s    = (const int*)d_in[9];
    const float* hb   = (const float*)d_in[10];
    const float* sk   = (const float*)d_in[11];
    const float* vb   = (const float*)d_in[12];
    const float* cb0  = (const float*)d_in[13];
    const float* ck0  = (const float*)d_in[14];
    const float* cb1  = (const float*)d_in[15];
    const float* ck1  = (const float*)d_in[16];
    const float* cb2  = (const float*)d_in[17];
    const float* ck2  = (const float*)d_in[18];
    const float* cb3  = (const float*)d_in[19];
    const float* ck3  = (const float*)d_in[20];
    const float* l0hb = (const float*)d_in[21];
    const float* l0k  = (const float*)d_in[22];
    const float* l1hb = (const float*)d_in[23];
    const float* l1k  = (const float*)d_in[24];

    ushort_t* wsu = (ushort_t*)d_ws;
    ushort_t* Wb  = wsu;                            // 4608*2464
    ushort_t* XA  = Wb + (size_t)NOUT * KPAD;       // 16384*2464
    ushort_t* LWb = XA + (size_t)B_ * KPAD;         // 4608*192
    ushort_t* CVL = LWb + (size_t)NOUT * KLOOP;     // 16384*192
    float* initb    = (float*)(CVL + (size_t)B_ * KLOOP);  // 16384
    float* partials = initb + B_;                          // 18*16384

    build_w<<<576, 256, 0, stream>>>(
        symm, c0s, c1s, c2s, c3s, sk, ck0, ck1, ck2, ck3, l0k, l1k, Wb, LWb);
    build_cv<<<B_, 256, 0, stream>>>(
        x, corr0, corr1, corr2, corr3, vb, cb0, cb1, cb2, cb3, XA, CVL, initb);
    mfma_gemm<<<2304, 256, 0, stream>>>(
        XA, Wb, CVL, LWb, hb, l0hb, l1hb, partials);
    finalize_out<<<B_ / 256, 256, 0, stream>>>(initb, partials, (float*)d_out);
}